// Round 4
// baseline (105.944 us; speedup 1.0000x reference)
//
#include <hip/hip_runtime.h>
#include <math.h>

// Problem constants: B=64, L=256, H=64
#define PB 64
#define PL 256
#define PH 64
#define TEMP 0.07f
#define NEG_INF_F (-1e9f)

#define KSTRIDE 72            // bf16 elements per staged K row (64 + 8 pad; 144 B, 16B-aligned)
#define KROWB   (KSTRIDE * 2) // 144 bytes per row
#define KSLAB   (PL * KSTRIDE)// elems per c slab (full 256 rows reserved)
#define BGRP    4             // b's per block in the scores kernel

typedef short short8 __attribute__((ext_vector_type(8)));   // 8 bf16 bit-patterns
typedef float f32x4 __attribute__((ext_vector_type(4)));

__device__ __forceinline__ unsigned short f32_to_bf16(float f) {
    unsigned int u = __float_as_uint(f);
    u += 0x7FFFu + ((u >> 16) & 1u);    // round to nearest even
    return (unsigned short)(u >> 16);
}

// ---------------- prep: Q bf16 convert + K compact/convert/pad ----------------
// blocks 0..255   : K compaction. c = bid>>2, quarter = bid&3 (rows q*64 .. q*64+63).
// blocks 256..511 : Q convert. b = (bid-256)>>2, quarter = (bid-256)&3.
__global__ __launch_bounds__(256)
void prep_kernel(const float* __restrict__ Q,
                 const float* __restrict__ K,
                 const int*   __restrict__ kmask,
                 unsigned short* __restrict__ Qb,
                 unsigned short* __restrict__ Kcomp,
                 int* __restrict__ nvK) {
    const int tid = threadIdx.x;

    if (blockIdx.x >= 256) {
        // ---- Q convert ----
        const int bb      = blockIdx.x - 256;
        const int b       = bb >> 2;
        const int quarter = bb & 3;
        const float4* src = (const float4*)(Q + (size_t)b * PL * PH) + quarter * 1024;
        unsigned short* dst = Qb + (size_t)b * PL * PH + quarter * 4096;
        #pragma unroll
        for (int it = 0; it < 4; ++it) {
            int i = it * 256 + tid;
            float4 v = src[i];
            ushort4 o;
            o.x = f32_to_bf16(v.x); o.y = f32_to_bf16(v.y);
            o.z = f32_to_bf16(v.z); o.w = f32_to_bf16(v.w);
            *(ushort4*)(dst + (size_t)i * 4) = o;
        }
        return;
    }

    // ---- K compaction ----
    const int c       = blockIdx.x >> 2;
    const int quarter = blockIdx.x & 3;
    const int lane = tid & 63;
    const int wave = tid >> 6;
    __shared__ int posArr[PL];
    __shared__ int wcnt[4];

    const int km = kmask[c * PL + tid];
    unsigned long long bal = __ballot(km != 0);
    int within = __popcll(bal & ((1ull << lane) - 1ull));
    if (lane == 0) wcnt[wave] = __popcll(bal);
    __syncthreads();
    int base = 0;
    #pragma unroll
    for (int w = 0; w < 4; ++w) base += (w < wave) ? wcnt[w] : 0;
    posArr[tid] = km ? (base + within) : -1;
    const int nv = wcnt[0] + wcnt[1] + wcnt[2] + wcnt[3];
    __syncthreads();

    unsigned short* slab = Kcomp + (size_t)c * KSLAB;
    const int sub = lane >> 4;     // row-within-group 0..3
    const int cl  = lane & 15;     // 16B column chunk

    // copy 64 rows: 4 waves x 4 rows/iter x 4 iters; 16 lanes per row.
    #pragma unroll
    for (int it = 0; it < 4; ++it) {
        int r = quarter * 64 + it * 16 + wave * 4 + sub;
        int p = posArr[r];
        if (p >= 0) {
            float4 v = *(const float4*)(K + ((size_t)c * PL + r) * PH + cl * 4);
            ushort4 o;
            o.x = f32_to_bf16(v.x); o.y = f32_to_bf16(v.y);
            o.z = f32_to_bf16(v.z); o.w = f32_to_bf16(v.w);
            *(ushort4*)(slab + (size_t)p * KSTRIDE + cl * 4) = o;
        }
    }

    // zero-fill tail pad rows up to multiple of 16 (only the owning quarter writes)
    const int rows16 = (nv + 15) & ~15;
    const int padChunks = (rows16 - nv) * 16;   // ushort4 chunks, <= 240
    if (tid < padChunks) {
        int row = nv + (tid >> 4);
        if (row >= quarter * 64 && row < quarter * 64 + 64) {
            *(ushort4*)(slab + (size_t)row * KSTRIDE + (tid & 15) * 4) = (ushort4){0, 0, 0, 0};
        }
    }
    if (quarter == 0 && tid == 0) nvK[c] = nv;
}

// ---------------- main scores kernel: one block per (c, b-group of 4) ----------------
// K_c staged into LDS ONCE, reused for BGRP=4 query batches. 64x16=1024 blocks,
// 36.9KB LDS -> 4 blocks/CU resident, single dispatch round, no barriers in b-loop.
__global__ __launch_bounds__(256)
void colbert_scores_mfma(const unsigned short* __restrict__ Qb,
                         const unsigned short* __restrict__ Kcomp,
                         const int*   __restrict__ nvK,
                         const int*   __restrict__ qmask,
                         float*       __restrict__ scores) {
    const int c  = blockIdx.x;
    const int bg = blockIdx.y;
    const int tid  = threadIdx.x;
    const int wave = tid >> 6;
    const int lane = tid & 63;
    const int n    = lane & 15;        // col / row-within-tile index
    const int g    = (lane >> 4) & 3;  // quad index

    __shared__ __align__(16) unsigned short Ks[PL * KSTRIDE];  // 36 KB
    __shared__ float red[BGRP][4];

    const int nv     = nvK[c];
    const int rows16 = (nv + 15) & ~15;
    const int nbytes = rows16 * KROWB;

    // Stage compacted K via async global->LDS (linear, padded layout identical on both sides).
    {
        const char* gsrc  = (const char*)(Kcomp + (size_t)c * KSLAB);
        char*       lbase = (char*)Ks;
        const int nchunks = (nbytes + 4095) >> 12;
        for (int it = 0; it < nchunks; ++it) {
            int off = it * 4096 + tid * 16;
            __builtin_amdgcn_global_load_lds(
                (const __attribute__((address_space(1))) unsigned int*)(gsrc + off),
                (__attribute__((address_space(3)))       unsigned int*)(lbase + off),
                16, 0, 0);
        }
    }

    __syncthreads();   // staging visible; K read-only from here on

    const f32x4 ZERO4 = (f32x4){0.f, 0.f, 0.f, 0.f};
    const int ntFull   = nv >> 4;
    const int tailCols = nv & 15;
    const int qw0 = wave * 64;
    const unsigned short* krow0 = &Ks[n * KSTRIDE + g * 8];

    #pragma unroll 1
    for (int bi = 0; bi < BGRP; ++bi) {
        const int b = bg * BGRP + bi;

        // A-fragments (Q) from global (L2-hot). lane holds A[m=lane&15][k=g*8+j].
        short8 afrag[4][2];
        {
            const unsigned short* Qrow = Qb + ((size_t)b * PL) * PH;
            #pragma unroll
            for (int rt = 0; rt < 4; ++rt) {
                const unsigned short* p = Qrow + (size_t)(qw0 + rt * 16 + n) * PH + g * 8;
                afrag[rt][0] = *(const short8*)(p);
                afrag[rt][1] = *(const short8*)(p + 32);
            }
        }

        float maxv[4][4];
        #pragma unroll
        for (int rt = 0; rt < 4; ++rt)
            #pragma unroll
            for (int r = 0; r < 4; ++r) maxv[rt][r] = NEG_INF_F;

        // main loop: pairs of full 16-col tiles
        int ct = 0;
        for (; ct + 1 < ntFull; ct += 2) {
            const unsigned short* ka = krow0 + ct * 16 * KSTRIDE;
            short8 kA0 = *(const short8*)(ka);
            short8 kA1 = *(const short8*)(ka + 32);
            short8 kB0 = *(const short8*)(ka + 16 * KSTRIDE);
            short8 kB1 = *(const short8*)(ka + 16 * KSTRIDE + 32);

            f32x4 accA[4], accB[4];
            #pragma unroll
            for (int rt = 0; rt < 4; ++rt) {
                accA[rt] = __builtin_amdgcn_mfma_f32_16x16x32_bf16(afrag[rt][0], kA0, ZERO4, 0, 0, 0);
                accB[rt] = __builtin_amdgcn_mfma_f32_16x16x32_bf16(afrag[rt][0], kB0, ZERO4, 0, 0, 0);
            }
            #pragma unroll
            for (int rt = 0; rt < 4; ++rt) {
                accA[rt] = __builtin_amdgcn_mfma_f32_16x16x32_bf16(afrag[rt][1], kA1, accA[rt], 0, 0, 0);
                accB[rt] = __builtin_amdgcn_mfma_f32_16x16x32_bf16(afrag[rt][1], kB1, accB[rt], 0, 0, 0);
            }
            #pragma unroll
            for (int rt = 0; rt < 4; ++rt)
                #pragma unroll
                for (int r = 0; r < 4; ++r)
                    maxv[rt][r] = fmaxf(maxv[rt][r], fmaxf(accA[rt][r], accB[rt][r]));
        }

        // leftover single full tile
        if (ntFull & 1) {
            const unsigned short* ka = krow0 + ct * 16 * KSTRIDE;
            short8 k0 = *(const short8*)(ka);
            short8 k1 = *(const short8*)(ka + 32);
            f32x4 acc[4];
            #pragma unroll
            for (int rt = 0; rt < 4; ++rt)
                acc[rt] = __builtin_amdgcn_mfma_f32_16x16x32_bf16(afrag[rt][0], k0, ZERO4, 0, 0, 0);
            #pragma unroll
            for (int rt = 0; rt < 4; ++rt)
                acc[rt] = __builtin_amdgcn_mfma_f32_16x16x32_bf16(afrag[rt][1], k1, acc[rt], 0, 0, 0);
            #pragma unroll
            for (int rt = 0; rt < 4; ++rt)
                #pragma unroll
                for (int r = 0; r < 4; ++r)
                    maxv[rt][r] = fmaxf(maxv[rt][r], acc[rt][r]);
            ct++;
        }

        // tail tile: pad lanes get NEG_INF via the MFMA C-operand bias
        if (tailCols) {
            float biasv = (n < tailCols) ? 0.0f : NEG_INF_F;
            f32x4 BIAS4 = (f32x4){biasv, biasv, biasv, biasv};
            const unsigned short* ka = krow0 + ct * 16 * KSTRIDE;
            short8 k0 = *(const short8*)(ka);
            short8 k1 = *(const short8*)(ka + 32);
            f32x4 acc[4];
            #pragma unroll
            for (int rt = 0; rt < 4; ++rt)
                acc[rt] = __builtin_amdgcn_mfma_f32_16x16x32_bf16(afrag[rt][0], k0, BIAS4, 0, 0, 0);
            #pragma unroll
            for (int rt = 0; rt < 4; ++rt)
                acc[rt] = __builtin_amdgcn_mfma_f32_16x16x32_bf16(afrag[rt][1], k1, acc[rt], 0, 0, 0);
            #pragma unroll
            for (int rt = 0; rt < 4; ++rt)
                #pragma unroll
                for (int r = 0; r < 4; ++r)
                    maxv[rt][r] = fmaxf(maxv[rt][r], acc[rt][r]);
        }

        // Max across the 16 lanes (cols) of each quad group.
        #pragma unroll
        for (int rt = 0; rt < 4; ++rt)
            #pragma unroll
            for (int r = 0; r < 4; ++r) {
                float mv = maxv[rt][r];
                mv = fmaxf(mv, __shfl_xor(mv, 1, 16));
                mv = fmaxf(mv, __shfl_xor(mv, 2, 16));
                mv = fmaxf(mv, __shfl_xor(mv, 4, 16));
                mv = fmaxf(mv, __shfl_xor(mv, 8, 16));
                maxv[rt][r] = mv;
            }

        // qmask-weighted sum; count each row once (n==0 lanes).
        float partial = 0.0f;
        if (n == 0) {
            const int* qm = qmask + b * PL;
            #pragma unroll
            for (int rt = 0; rt < 4; ++rt)
                #pragma unroll
                for (int r = 0; r < 4; ++r) {
                    int row = qw0 + rt * 16 + g * 4 + r;
                    partial += maxv[rt][r] * (float)qm[row];
                }
        }
        partial += __shfl_xor(partial, 16, 64);
        partial += __shfl_xor(partial, 32, 64);
        if (lane == 0) red[bi][wave] = partial;
    }

    __syncthreads();
    if (tid < BGRP) {
        float total = red[tid][0] + red[tid][1] + red[tid][2] + red[tid][3];
        scores[(bg * BGRP + tid) * PB + c] = total * (1.0f / TEMP);
    }
}

// ---------------- finalize: log-softmax CE ----------------
__global__ void finalize_kernel(const float* __restrict__ scores,
                                const int*   __restrict__ labels,
                                float*       __restrict__ out) {
    const int r = threadIdx.x;   // 64 threads, one per row
    const float* row = scores + r * PB;
    float mx = NEG_INF_F;
    for (int j = 0; j < PB; ++j) mx = fmaxf(mx, row[j]);
    float se = 0.0f;
    for (int j = 0; j < PB; ++j) se += expf(row[j] - mx);
    float logp_diag = row[r] - mx - logf(se);
    float w = (float)labels[r];
    float wd = w * logp_diag;
    #pragma unroll
    for (int off = 32; off >= 1; off >>= 1) {
        wd += __shfl_xor(wd, off, 64);
        w  += __shfl_xor(w,  off, 64);
    }
    if (r == 0) out[0] = -wd / fmaxf(w, 1.0f);
}

extern "C" void kernel_launch(void* const* d_in, const int* in_sizes, int n_in,
                              void* d_out, int out_size, void* d_ws, size_t ws_size,
                              hipStream_t stream) {
    const float* Q      = (const float*)d_in[0];
    const float* K      = (const float*)d_in[1];
    const int*   labels = (const int*)d_in[2];
    const int*   qmask  = (const int*)d_in[3];
    const int*   kmask  = (const int*)d_in[4];
    float*       out    = (float*)d_out;

    // ws layout: [scores 16KB][Qb 2MB][Kcomp 2.25MB][nvK 256B]
    char* ws = (char*)d_ws;
    float*          scores = (float*)ws;
    unsigned short* Qb     = (unsigned short*)(ws + 16 * 1024);
    unsigned short* Kcomp  = (unsigned short*)(ws + 16 * 1024 + 2 * 1024 * 1024);
    int*            nvK    = (int*)(ws + 16 * 1024 + 2 * 1024 * 1024 + (size_t)PB * KSLAB * 2);

    prep_kernel<<<512, 256, 0, stream>>>(Q, K, kmask, Qb, Kcomp, nvK);

    dim3 grid(PB, PB / BGRP);
    colbert_scores_mfma<<<grid, 256, 0, stream>>>(Qb, Kcomp, nvK, qmask, scores);
    finalize_kernel<<<1, 64, 0, stream>>>(scores, labels, out);
}

// Round 5
// 96.180 us; speedup vs baseline: 1.1015x; 1.1015x over previous
//
#include <hip/hip_runtime.h>
#include <math.h>

// Problem constants: B=64, L=256, H=64
#define PB 64
#define PL 256
#define PH 64
#define TEMP 0.07f
#define NEG_INF_F (-1e9f)

#define KSTRIDE 72            // bf16 elements per staged K row (64 + 8 pad; 144 B, 16B-aligned)
#define KROWB   (KSTRIDE * 2) // 144 bytes per row
#define KSLAB   (PL * KSTRIDE)// elems per c slab (full 256 rows reserved)
#define BGRP    2             // b's per block in the scores kernel

typedef short short8 __attribute__((ext_vector_type(8)));   // 8 bf16 bit-patterns
typedef float f32x4 __attribute__((ext_vector_type(4)));

__device__ __forceinline__ unsigned short f32_to_bf16(float f) {
    unsigned int u = __float_as_uint(f);
    u += 0x7FFFu + ((u >> 16) & 1u);    // round to nearest even
    return (unsigned short)(u >> 16);
}

// ---------------- prep: K AND Q compact/convert/pad ----------------
// blocks 0..255   : K compaction. c = bid>>2, quarter = bid&3. Valid kmask rows,
//                   KSTRIDE-padded, tail zero rows to multiple of 16; nvK[c].
// blocks 256..511 : Q compaction. b = (bid-256)>>2, quarter = (bid-256)&3. Valid
//                   qmask rows, dense PH stride, ALL rows >= nvQ zero-filled; nvQ[b].
__global__ __launch_bounds__(256)
void prep_kernel(const float* __restrict__ Q,
                 const float* __restrict__ K,
                 const int*   __restrict__ kmask,
                 const int*   __restrict__ qmask,
                 unsigned short* __restrict__ Qcomp,
                 unsigned short* __restrict__ Kcomp,
                 int* __restrict__ nvK,
                 int* __restrict__ nvQ) {
    const int tid  = threadIdx.x;
    const int lane = tid & 63;
    const int wave = tid >> 6;
    __shared__ int posArr[PL];
    __shared__ int wcnt[4];

    const bool isQ = (blockIdx.x >= 256);
    const int  bid = isQ ? (blockIdx.x - 256) : blockIdx.x;
    const int  idx     = bid >> 2;     // c or b
    const int  quarter = bid & 3;

    const int* mask = isQ ? (qmask + idx * PL) : (kmask + idx * PL);
    const int km = mask[tid];
    unsigned long long bal = __ballot(km != 0);
    int within = __popcll(bal & ((1ull << lane) - 1ull));
    if (lane == 0) wcnt[wave] = __popcll(bal);
    __syncthreads();
    int base = 0;
    #pragma unroll
    for (int w = 0; w < 4; ++w) base += (w < wave) ? wcnt[w] : 0;
    posArr[tid] = km ? (base + within) : -1;
    const int nv = wcnt[0] + wcnt[1] + wcnt[2] + wcnt[3];
    __syncthreads();

    const int sub = lane >> 4;     // row-within-group 0..3
    const int cl  = lane & 15;     // 16B column chunk
    const float* src = (isQ ? Q : K) + (size_t)idx * PL * PH;

    if (!isQ) {
        unsigned short* slab = Kcomp + (size_t)idx * KSLAB;
        #pragma unroll
        for (int it = 0; it < 4; ++it) {
            int r = quarter * 64 + it * 16 + wave * 4 + sub;
            int p = posArr[r];
            if (p >= 0) {
                float4 v = *(const float4*)(src + (size_t)r * PH + cl * 4);
                ushort4 o;
                o.x = f32_to_bf16(v.x); o.y = f32_to_bf16(v.y);
                o.z = f32_to_bf16(v.z); o.w = f32_to_bf16(v.w);
                *(ushort4*)(slab + (size_t)p * KSTRIDE + cl * 4) = o;
            }
        }
        // zero tail pad rows up to multiple of 16 (<=240 chunks, single shot)
        const int rows16 = (nv + 15) & ~15;
        const int padChunks = (rows16 - nv) * 16;
        if (tid < padChunks) {
            int row = nv + (tid >> 4);
            if (row >= quarter * 64 && row < quarter * 64 + 64)
                *(ushort4*)(slab + (size_t)row * KSTRIDE + (tid & 15) * 4) = (ushort4){0, 0, 0, 0};
        }
        if (quarter == 0 && tid == 0) nvK[idx] = nv;
    } else {
        unsigned short* slab = Qcomp + (size_t)idx * PL * PH;
        #pragma unroll
        for (int it = 0; it < 4; ++it) {
            int r = quarter * 64 + it * 16 + wave * 4 + sub;
            int p = posArr[r];
            if (p >= 0) {
                float4 v = *(const float4*)(src + (size_t)r * PH + cl * 4);
                ushort4 o;
                o.x = f32_to_bf16(v.x); o.y = f32_to_bf16(v.y);
                o.z = f32_to_bf16(v.z); o.w = f32_to_bf16(v.w);
                *(ushort4*)(slab + (size_t)p * PH + cl * 4) = o;
            }
        }
        // zero-fill ALL rows >= nv inside this quarter's row window (1024 chunks / 4 iters)
        #pragma unroll
        for (int it = 0; it < 4; ++it) {
            int id2 = it * 256 + tid;            // 0..1023: (row-in-quarter, chunk)
            int row = quarter * 64 + (id2 >> 4);
            if (row >= nv)
                *(ushort4*)(slab + (size_t)row * PH + (id2 & 15) * 4) = (ushort4){0, 0, 0, 0};
        }
        if (quarter == 0 && tid == 0) nvQ[idx] = nv;
    }
}

// ---------------- main scores kernel: one block per (c, b-pair) ----------------
// K_c staged to LDS once; q-tile-PAIRS (32 rows) distributed over 4 waves; both b's
// of the pair share the K fragments -> 16 MFMA per 4 ds_read_b128.
__global__ __launch_bounds__(256)
void colbert_scores_mfma(const unsigned short* __restrict__ Qcomp,
                         const unsigned short* __restrict__ Kcomp,
                         const int*   __restrict__ nvK,
                         const int*   __restrict__ nvQ,
                         float*       __restrict__ scores) {
    const int c  = blockIdx.x;
    const int bg = blockIdx.y;
    const int tid  = threadIdx.x;
    const int wave = tid >> 6;
    const int lane = tid & 63;
    const int n    = lane & 15;        // col / row-within-tile index
    const int g    = (lane >> 4) & 3;  // quad index

    __shared__ __align__(16) unsigned short Ks[PL * KSTRIDE];  // 36 KB
    __shared__ float red[BGRP][4];

    const int nv     = nvK[c];
    const int rows16 = (nv + 15) & ~15;
    const int nbytes = rows16 * KROWB;

    // Stage compacted K via async global->LDS (linear, layout identical both sides).
    {
        const char* gsrc  = (const char*)(Kcomp + (size_t)c * KSLAB);
        char*       lbase = (char*)Ks;
        const int nchunks = (nbytes + 4095) >> 12;
        for (int it = 0; it < nchunks; ++it) {
            int off = it * 4096 + tid * 16;
            __builtin_amdgcn_global_load_lds(
                (const __attribute__((address_space(1))) unsigned int*)(gsrc + off),
                (__attribute__((address_space(3)))       unsigned int*)(lbase + off),
                16, 0, 0);
        }
    }

    const int b0 = bg * BGRP;
    const int nq0 = nvQ[b0];
    const int nq1 = nvQ[b0 + 1];
    const int ntQP = ((max(nq0, nq1)) + 31) >> 5;   // q-tile-pairs (32 rows each)

    __syncthreads();   // staging visible; K read-only from here on

    const f32x4 ZERO4 = (f32x4){0.f, 0.f, 0.f, 0.f};
    const int ntFull   = nv >> 4;
    const int tailCols = nv & 15;
    const unsigned short* krow0 = &Ks[n * KSTRIDE + g * 8];
    const float biasv = (n < tailCols) ? 0.0f : NEG_INF_F;
    const f32x4 BIAS4 = (f32x4){biasv, biasv, biasv, biasv};

    float partial[BGRP] = {0.0f, 0.0f};

    for (int qp = wave; qp < ntQP; qp += 4) {
        // A-fragments for both b's, both q-tiles of the pair (zero rows beyond nvQ -> +0)
        short8 aA[BGRP][2][2];
        #pragma unroll
        for (int bi = 0; bi < BGRP; ++bi) {
            const unsigned short* Qrow = Qcomp + ((size_t)(b0 + bi) * PL + qp * 32 + n) * PH + g * 8;
            aA[bi][0][0] = *(const short8*)(Qrow);
            aA[bi][0][1] = *(const short8*)(Qrow + 32);
            aA[bi][1][0] = *(const short8*)(Qrow + 16 * PH);
            aA[bi][1][1] = *(const short8*)(Qrow + 16 * PH + 32);
        }

        float maxv[BGRP][2][4];
        #pragma unroll
        for (int bi = 0; bi < BGRP; ++bi)
            #pragma unroll
            for (int t = 0; t < 2; ++t)
                #pragma unroll
                for (int r = 0; r < 4; ++r) maxv[bi][t][r] = NEG_INF_F;

        int ct = 0;
        for (; ct + 1 < ntFull; ct += 2) {
            const unsigned short* ka = krow0 + ct * 16 * KSTRIDE;
            short8 kA0 = *(const short8*)(ka);
            short8 kA1 = *(const short8*)(ka + 32);
            short8 kB0 = *(const short8*)(ka + 16 * KSTRIDE);
            short8 kB1 = *(const short8*)(ka + 16 * KSTRIDE + 32);

            #pragma unroll
            for (int bi = 0; bi < BGRP; ++bi)
                #pragma unroll
                for (int t = 0; t < 2; ++t) {
                    f32x4 accA = __builtin_amdgcn_mfma_f32_16x16x32_bf16(aA[bi][t][0], kA0, ZERO4, 0, 0, 0);
                    accA = __builtin_amdgcn_mfma_f32_16x16x32_bf16(aA[bi][t][1], kA1, accA, 0, 0, 0);
                    f32x4 accB = __builtin_amdgcn_mfma_f32_16x16x32_bf16(aA[bi][t][0], kB0, ZERO4, 0, 0, 0);
                    accB = __builtin_amdgcn_mfma_f32_16x16x32_bf16(aA[bi][t][1], kB1, accB, 0, 0, 0);
                    #pragma unroll
                    for (int r = 0; r < 4; ++r)
                        maxv[bi][t][r] = fmaxf(maxv[bi][t][r], fmaxf(accA[r], accB[r]));
                }
        }

        if (ntFull & 1) {
            const unsigned short* ka = krow0 + ct * 16 * KSTRIDE;
            short8 k0 = *(const short8*)(ka);
            short8 k1 = *(const short8*)(ka + 32);
            #pragma unroll
            for (int bi = 0; bi < BGRP; ++bi)
                #pragma unroll
                for (int t = 0; t < 2; ++t) {
                    f32x4 acc = __builtin_amdgcn_mfma_f32_16x16x32_bf16(aA[bi][t][0], k0, ZERO4, 0, 0, 0);
                    acc = __builtin_amdgcn_mfma_f32_16x16x32_bf16(aA[bi][t][1], k1, acc, 0, 0, 0);
                    #pragma unroll
                    for (int r = 0; r < 4; ++r)
                        maxv[bi][t][r] = fmaxf(maxv[bi][t][r], acc[r]);
                }
            ct++;
        }

        if (tailCols) {
            const unsigned short* ka = krow0 + ct * 16 * KSTRIDE;
            short8 k0 = *(const short8*)(ka);
            short8 k1 = *(const short8*)(ka + 32);
            #pragma unroll
            for (int bi = 0; bi < BGRP; ++bi)
                #pragma unroll
                for (int t = 0; t < 2; ++t) {
                    f32x4 acc = __builtin_amdgcn_mfma_f32_16x16x32_bf16(aA[bi][t][0], k0, BIAS4, 0, 0, 0);
                    acc = __builtin_amdgcn_mfma_f32_16x16x32_bf16(aA[bi][t][1], k1, acc, 0, 0, 0);
                    #pragma unroll
                    for (int r = 0; r < 4; ++r)
                        maxv[bi][t][r] = fmaxf(maxv[bi][t][r], acc[r]);
                }
        }

        // col-reduce over the 16 lanes of each quad group, then accumulate row sums
        #pragma unroll
        for (int bi = 0; bi < BGRP; ++bi)
            #pragma unroll
            for (int t = 0; t < 2; ++t)
                #pragma unroll
                for (int r = 0; r < 4; ++r) {
                    float mv = maxv[bi][t][r];
                    mv = fmaxf(mv, __shfl_xor(mv, 1, 16));
                    mv = fmaxf(mv, __shfl_xor(mv, 2, 16));
                    mv = fmaxf(mv, __shfl_xor(mv, 4, 16));
                    mv = fmaxf(mv, __shfl_xor(mv, 8, 16));
                    if (n == 0) partial[bi] += mv;   // each (g,t,r) = one distinct q row
                }
    }

    #pragma unroll
    for (int bi = 0; bi < BGRP; ++bi) {
        float p = partial[bi];
        p += __shfl_xor(p, 16, 64);
        p += __shfl_xor(p, 32, 64);
        if (lane == 0) red[bi][wave] = p;
    }

    __syncthreads();
    if (tid < BGRP) {
        float total = red[tid][0] + red[tid][1] + red[tid][2] + red[tid][3];
        scores[(b0 + tid) * PB + c] = total * (1.0f / TEMP);
    }
}

// ---------------- finalize: log-softmax CE ----------------
__global__ void finalize_kernel(const float* __restrict__ scores,
                                const int*   __restrict__ labels,
                                float*       __restrict__ out) {
    const int r = threadIdx.x;   // 64 threads, one per row
    const float* row = scores + r * PB;
    float mx = NEG_INF_F;
    for (int j = 0; j < PB; ++j) mx = fmaxf(mx, row[j]);
    float se = 0.0f;
    for (int j = 0; j < PB; ++j) se += expf(row[j] - mx);
    float logp_diag = row[r] - mx - logf(se);
    float w = (float)labels[r];
    float wd = w * logp_diag;
    #pragma unroll
    for (int off = 32; off >= 1; off >>= 1) {
        wd += __shfl_xor(wd, off, 64);
        w  += __shfl_xor(w,  off, 64);
    }
    if (r == 0) out[0] = -wd / fmaxf(w, 1.0f);
}

extern "C" void kernel_launch(void* const* d_in, const int* in_sizes, int n_in,
                              void* d_out, int out_size, void* d_ws, size_t ws_size,
                              hipStream_t stream) {
    const float* Q      = (const float*)d_in[0];
    const float* K      = (const float*)d_in[1];
    const int*   labels = (const int*)d_in[2];
    const int*   qmask  = (const int*)d_in[3];
    const int*   kmask  = (const int*)d_in[4];
    float*       out    = (float*)d_out;

    // ws layout: [scores 16KB][Qcomp 2MB][Kcomp 2.25MB][nvK 256B][nvQ 256B]
    char* ws = (char*)d_ws;
    float*          scores = (float*)ws;
    unsigned short* Qcomp  = (unsigned short*)(ws + 16 * 1024);
    unsigned short* Kcomp  = (unsigned short*)(ws + 16 * 1024 + 2 * 1024 * 1024);
    int*            nvK    = (int*)(ws + 16 * 1024 + 2 * 1024 * 1024 + (size_t)PB * KSLAB * 2);
    int*            nvQ    = nvK + 64;

    prep_kernel<<<512, 256, 0, stream>>>(Q, K, kmask, qmask, Qcomp, Kcomp, nvK, nvQ);

    dim3 grid(PB, PB / BGRP);
    colbert_scores_mfma<<<grid, 256, 0, stream>>>(Qcomp, Kcomp, nvK, nvQ, scores);
    finalize_kernel<<<1, 64, 0, stream>>>(scores, labels, out);
}